// Round 1
// baseline (435.896 us; speedup 1.0000x reference)
//
#include <hip/hip_runtime.h>
#include <hip/hip_bf16.h>
#include <stdint.h>
#include <stddef.h>

// Problem constants
#define D_DIM 2048
#define H_HEADS 16
#define KV_HEADS 4
#define HEAD_DIM 128
#define SEQ_L 2048
#define BATCH 2
#define NTOK 4096      // BATCH*SEQ_L
#define NQKV 3072      // D + 2*KV_HEADS*HEAD_DIM

typedef __attribute__((ext_vector_type(4))) float f32x4;
typedef __attribute__((ext_vector_type(8))) short bf16x8;

__device__ __forceinline__ unsigned short f2bf(float f) {
  unsigned int u = __float_as_uint(f);
  unsigned int r = u + 0x7fffu + ((u >> 16) & 1u);   // RTNE
  return (unsigned short)(r >> 16);
}
__device__ __forceinline__ float bf2f(unsigned short s) {
  return __uint_as_float(((unsigned int)s) << 16);
}

__device__ __forceinline__ void async_copy16(const void* g, void* l) {
  __builtin_amdgcn_global_load_lds(
      (__attribute__((address_space(1))) void*)(g),
      (__attribute__((address_space(3))) void*)(l),
      16, 0, 0);
}

// ---------------- fp32 -> bf16 cast ----------------
__global__ __launch_bounds__(256) void cast_kernel(const float* __restrict__ src,
                                                   unsigned short* __restrict__ dst, int n) {
  int idx = blockIdx.x * blockDim.x + threadIdx.x;
  int stride = gridDim.x * blockDim.x;
  for (int i = idx * 4; i < n; i += stride * 4) {
    float4 v = *reinterpret_cast<const float4*>(src + i);
    ushort4 o;
    o.x = f2bf(v.x); o.y = f2bf(v.y); o.z = f2bf(v.z); o.w = f2bf(v.w);
    *reinterpret_cast<ushort4*>(dst + i) = o;
  }
}

// ---------------- RoPE table ----------------
__global__ __launch_bounds__(256) void rope_table_kernel(float* __restrict__ cosT,
                                                         float* __restrict__ sinT) {
  int i = blockIdx.x * blockDim.x + threadIdx.x;  // l*64 + p
  if (i >= SEQ_L * 64) return;
  int p = i & 63;
  float l = (float)(i >> 6);
  float inv = powf(10000.0f, -(float)p / 64.0f);
  float ang = l * inv;
  cosT[i] = cosf(ang);
  sinT[i] = sinf(ang);
}

// ---------------- GEMM: C[M,N] = A[M,K] * B[N,K]^T  (bf16 in, OutT out) ----------------
__device__ __forceinline__ void store_out(unsigned short* p, float v) { *p = f2bf(v); }
__device__ __forceinline__ void store_out(float* p, float v) { *p = v; }

template <typename OutT>
__global__ __launch_bounds__(256) void gemm_bt_kernel(const unsigned short* __restrict__ A,
                                                      const unsigned short* __restrict__ B,
                                                      OutT* __restrict__ C,
                                                      int M, int N, int K) {
  __shared__ unsigned short Alds[128 * 32];
  __shared__ unsigned short Blds[128 * 32];
  const int tid = threadIdx.x;
  const int wave = tid >> 6;
  const int lane = tid & 63;
  const int l15 = lane & 15;
  const int l4 = lane >> 4;
  const int m0 = blockIdx.x * 128;
  const int n0 = blockIdx.y * 128;
  const int wm = (wave >> 1) * 64;
  const int wn = (wave & 1) * 64;

  f32x4 acc[4][4] = {};

  const int soff0 = wave * 1024 + lane * 16;  // bytes within 8KB tile

  for (int kt = 0; kt < K; kt += 32) {
#pragma unroll
    for (int inst = 0; inst < 2; ++inst) {
      int off = soff0 + inst * 4096;
      int row = off >> 6;    // 64 bytes (32 bf16) per LDS row
      int colb = off & 63;
      const char* ga = (const char*)(A + (size_t)(m0 + row) * K + kt) + colb;
      async_copy16(ga, (char*)Alds + off);
      const char* gb = (const char*)(B + (size_t)(n0 + row) * K + kt) + colb;
      async_copy16(gb, (char*)Blds + off);
    }
    __syncthreads();
    bf16x8 af[4], bfr[4];
#pragma unroll
    for (int i = 0; i < 4; ++i)
      af[i] = *reinterpret_cast<const bf16x8*>(Alds + (wm + i * 16 + l15) * 32 + l4 * 8);
#pragma unroll
    for (int j = 0; j < 4; ++j)
      bfr[j] = *reinterpret_cast<const bf16x8*>(Blds + (wn + j * 16 + l15) * 32 + l4 * 8);
#pragma unroll
    for (int i = 0; i < 4; ++i)
#pragma unroll
      for (int j = 0; j < 4; ++j)
        acc[i][j] = __builtin_amdgcn_mfma_f32_16x16x32_bf16(af[i], bfr[j], acc[i][j], 0, 0, 0);
    __syncthreads();
  }

#pragma unroll
  for (int i = 0; i < 4; ++i)
#pragma unroll
    for (int j = 0; j < 4; ++j) {
      int col = n0 + wn + j * 16 + l15;
#pragma unroll
      for (int r = 0; r < 4; ++r) {
        int row = m0 + wm + i * 16 + l4 * 4 + r;
        store_out(C + (size_t)row * N + col, acc[i][j][r]);
      }
    }
}

// ---------------- RMSNorm + RoPE (in-place on QKV buffer) ----------------
__global__ __launch_bounds__(256) void norm_rope_kernel(unsigned short* __restrict__ qkv,
                                                        const float* __restrict__ qw,
                                                        const float* __restrict__ kw,
                                                        const float* __restrict__ cosT,
                                                        const float* __restrict__ sinT) {
  int wid = (blockIdx.x * blockDim.x + threadIdx.x) >> 6;  // global wave id
  int lane = threadIdx.x & 63;
  unsigned short* rowp;
  const float* w;
  int m;
  if (wid < NTOK * H_HEADS) {
    m = wid >> 4;
    int hh = wid & 15;
    rowp = qkv + (size_t)m * NQKV + hh * HEAD_DIM;
    w = qw;
  } else {
    int r2 = wid - NTOK * H_HEADS;
    m = r2 >> 2;
    int kvh = r2 & 3;
    rowp = qkv + (size_t)m * NQKV + D_DIM + kvh * HEAD_DIM;
    w = kw;
  }
  int l = m & (SEQ_L - 1);
  unsigned int pair = *reinterpret_cast<const unsigned int*>(rowp + lane * 2);
  float e = bf2f((unsigned short)(pair & 0xffffu));
  float o = bf2f((unsigned short)(pair >> 16));
  float ss = e * e + o * o;
#pragma unroll
  for (int off = 1; off < 64; off <<= 1) ss += __shfl_xor(ss, off);
  float rsn = rsqrtf(ss * (1.0f / 128.0f) + 1e-6f);
  float we = w[lane * 2], wo_ = w[lane * 2 + 1];
  float c = cosT[l * 64 + lane], s = sinT[l * 64 + lane];
  float xe = e * rsn * we, xo = o * rsn * wo_;
  float re = xe * c - xo * s;
  float ro = xe * s + xo * c;
  unsigned int opack = (unsigned int)f2bf(re) | ((unsigned int)f2bf(ro) << 16);
  *reinterpret_cast<unsigned int*>(rowp + lane * 2) = opack;
}

// ---------------- Flash attention (causal, GQA) ----------------
// Block: 256 threads = 4 waves. Each block: one (b,h), 64 q rows; each wave 16 q rows.
__global__ __launch_bounds__(256) void attn_kernel(const unsigned short* __restrict__ qkv,
                                                   unsigned short* __restrict__ obuf) {
  __shared__ unsigned short Klds[64 * 136];      // keys x HD, pad 128->136
  __shared__ unsigned short Vt[128 * 72];        // d x keys, pad 64->72
  __shared__ unsigned short Plds[4][16 * 72];    // per-wave P tile, pad 64->72

  const int tid = threadIdx.x;
  const int wave = tid >> 6, lane = tid & 63;
  const int l15 = lane & 15, l4 = lane >> 4;
  const int q0 = blockIdx.x * 64;
  const int bh = blockIdx.y;
  const int b = bh >> 4, h = bh & 15;
  const int kvh = h >> 2;

  const size_t base = (size_t)b * SEQ_L * NQKV;
  const unsigned short* Kg = qkv + base + D_DIM + kvh * HEAD_DIM;
  const unsigned short* Vg = qkv + base + D_DIM + KV_HEADS * HEAD_DIM + kvh * HEAD_DIM;

  // Q fragments: wave's rows q0+wave*16+l15
  bf16x8 qf[4];
  {
    const unsigned short* qrow = qkv + base + (size_t)(q0 + wave * 16 + l15) * NQKV + h * HEAD_DIM;
#pragma unroll
    for (int kk = 0; kk < 4; ++kk)
      qf[kk] = *reinterpret_cast<const bf16x8*>(qrow + kk * 32 + l4 * 8);
  }

  f32x4 accO[8];
#pragma unroll
  for (int jd = 0; jd < 8; ++jd) accO[jd] = f32x4{0.f, 0.f, 0.f, 0.f};
  float mrun[4], lrun[4];
#pragma unroll
  for (int r = 0; r < 4; ++r) { mrun[r] = -1e30f; lrun[r] = 0.0f; }

  const int nkt = q0 / 64;  // inclusive last kv-tile
  const float scale = 0.08838834764831845f;  // 1/sqrt(128)

  for (int kt = 0; kt <= nkt; ++kt) {
    // stage K tile (coalesced, padded rows)
#pragma unroll
    for (int i = 0; i < 4; ++i) {
      int c = tid + i * 256;           // 1024 chunks of 16B
      int row = c >> 4, sub = c & 15;
      bf16x8 v = *reinterpret_cast<const bf16x8*>(Kg + (size_t)(kt * 64 + row) * NQKV + sub * 8);
      *reinterpret_cast<bf16x8*>(&Klds[row * 136 + sub * 8]) = v;
    }
    // stage V transposed: Vt[d][key]
#pragma unroll
    for (int i = 0; i < 2; ++i) {
      int task = tid + i * 256;        // 512 tasks
      int kp = task & 31, dc = task >> 5;
      const unsigned short* v0p = Vg + (size_t)(kt * 64 + 2 * kp) * NQKV + dc * 8;
      bf16x8 v0 = *reinterpret_cast<const bf16x8*>(v0p);
      bf16x8 v1 = *reinterpret_cast<const bf16x8*>(v0p + NQKV);
#pragma unroll
      for (int e = 0; e < 8; ++e) {
        int d = dc * 8 + e;
        unsigned int pack = (unsigned int)(unsigned short)v0[e] |
                            ((unsigned int)(unsigned short)v1[e] << 16);
        *reinterpret_cast<unsigned int*>(&Vt[d * 72 + kp * 2]) = pack;
      }
    }
    __syncthreads();

    // S = Q K^T : 16 q rows x 64 keys
    f32x4 sv[4];
#pragma unroll
    for (int j = 0; j < 4; ++j) sv[j] = f32x4{0.f, 0.f, 0.f, 0.f};
#pragma unroll
    for (int kk = 0; kk < 4; ++kk) {
#pragma unroll
      for (int j = 0; j < 4; ++j) {
        bf16x8 kf = *reinterpret_cast<const bf16x8*>(&Klds[(j * 16 + l15) * 136 + kk * 32 + l4 * 8]);
        sv[j] = __builtin_amdgcn_mfma_f32_16x16x32_bf16(qf[kk], kf, sv[j], 0, 0, 0);
      }
    }

    // mask + scale + online softmax (per r: q row = q0 + wave*16 + l4*4 + r)
    const int qrow_base = q0 + wave * 16 + l4 * 4;
    float corr[4];
#pragma unroll
    for (int r = 0; r < 4; ++r) {
      int q = qrow_base + r;
      float tm = -1e30f;
#pragma unroll
      for (int j = 0; j < 4; ++j) {
        int key = kt * 64 + j * 16 + l15;
        float s = sv[j][r] * scale;
        s = (key <= q) ? s : -1e30f;
        sv[j][r] = s;
        tm = fmaxf(tm, s);
      }
#pragma unroll
      for (int off = 1; off < 16; off <<= 1) tm = fmaxf(tm, __shfl_xor(tm, off));
      float mnew = fmaxf(mrun[r], tm);
      corr[r] = __expf(mrun[r] - mnew);
      mrun[r] = mnew;
      float rs = 0.f;
#pragma unroll
      for (int j = 0; j < 4; ++j) {
        float p = __expf(sv[j][r] - mnew);
        sv[j][r] = p;
        rs += p;
      }
#pragma unroll
      for (int off = 1; off < 16; off <<= 1) rs += __shfl_xor(rs, off);
      lrun[r] = lrun[r] * corr[r] + rs;
    }
#pragma unroll
    for (int jd = 0; jd < 8; ++jd)
#pragma unroll
      for (int r = 0; r < 4; ++r) accO[jd][r] *= corr[r];

    // P -> LDS (C-layout scatter), then read back in A-operand layout
#pragma unroll
    for (int r = 0; r < 4; ++r)
#pragma unroll
      for (int j = 0; j < 4; ++j)
        Plds[wave][(l4 * 4 + r) * 72 + j * 16 + l15] = f2bf(sv[j][r]);

    // PV: O += P V
#pragma unroll
    for (int ks = 0; ks < 2; ++ks) {
      bf16x8 pf = *reinterpret_cast<const bf16x8*>(&Plds[wave][l15 * 72 + ks * 32 + l4 * 8]);
#pragma unroll
      for (int jd = 0; jd < 8; ++jd) {
        bf16x8 vf = *reinterpret_cast<const bf16x8*>(&Vt[(jd * 16 + l15) * 72 + ks * 32 + l4 * 8]);
        accO[jd] = __builtin_amdgcn_mfma_f32_16x16x32_bf16(pf, vf, accO[jd], 0, 0, 0);
      }
    }
    __syncthreads();
  }

  // epilogue: O / l
#pragma unroll
  for (int r = 0; r < 4; ++r) {
    float inv = 1.0f / lrun[r];
    int row = q0 + wave * 16 + l4 * 4 + r;
    size_t orow = ((size_t)b * SEQ_L + row) * (size_t)D_DIM + h * HEAD_DIM;
#pragma unroll
    for (int jd = 0; jd < 8; ++jd)
      obuf[orow + jd * 16 + l15] = f2bf(accO[jd][r] * inv);
  }
}

// ---------------- launcher ----------------
extern "C" void kernel_launch(void* const* d_in, const int* in_sizes, int n_in,
                              void* d_out, int out_size, void* d_ws, size_t ws_size,
                              hipStream_t stream) {
  const float* x   = (const float*)d_in[0];
  const float* wq  = (const float*)d_in[1];
  const float* wk  = (const float*)d_in[2];
  const float* wv  = (const float*)d_in[3];
  const float* wo  = (const float*)d_in[4];
  const float* qnw = (const float*)d_in[5];
  const float* knw = (const float*)d_in[6];
  float* out = (float*)d_out;

  char* ws = (char*)d_ws;
  unsigned short* Xb    = (unsigned short*)(ws);                    // 4096x2048 bf16
  unsigned short* Wqkvb = (unsigned short*)(ws + 16777216);         // 3072x2048 bf16
  unsigned short* Wob   = (unsigned short*)(ws + 29360128);         // 2048x2048 bf16
  unsigned short* QKV   = (unsigned short*)(ws + 37748736);         // 4096x3072 bf16
  unsigned short* Obuf  = (unsigned short*)(ws + 62914560);         // 4096x2048 bf16
  float* cosT = (float*)(ws + 79691776);                            // 2048x64 f32
  float* sinT = (float*)(ws + 80216064);

  cast_kernel<<<1024, 256, 0, stream>>>(x, Xb, NTOK * D_DIM);
  cast_kernel<<<1024, 256, 0, stream>>>(wq, Wqkvb, D_DIM * D_DIM);
  cast_kernel<<<256, 256, 0, stream>>>(wk, Wqkvb + (size_t)D_DIM * D_DIM, 512 * D_DIM);
  cast_kernel<<<256, 256, 0, stream>>>(wv, Wqkvb + (size_t)2560 * D_DIM, 512 * D_DIM);
  cast_kernel<<<1024, 256, 0, stream>>>(wo, Wob, D_DIM * D_DIM);
  rope_table_kernel<<<512, 256, 0, stream>>>(cosT, sinT);

  dim3 g1(NTOK / 128, NQKV / 128);
  gemm_bt_kernel<unsigned short><<<g1, 256, 0, stream>>>(Xb, Wqkvb, QKV, NTOK, NQKV, D_DIM);

  norm_rope_kernel<<<(NTOK * (H_HEADS + KV_HEADS)) / 4, 256, 0, stream>>>(QKV, qnw, knw, cosT, sinT);

  attn_kernel<<<dim3(SEQ_L / 64, BATCH * H_HEADS), 256, 0, stream>>>(QKV, Obuf);

  dim3 g2(NTOK / 128, D_DIM / 128);
  gemm_bt_kernel<float><<<g2, 256, 0, stream>>>(Obuf, Wob, out, NTOK, D_DIM, D_DIM);
}